// Round 2
// baseline (609.531 us; speedup 1.0000x reference)
//
#include <hip/hip_runtime.h>

// PluginEmbedding: CSR sparse-embedding lookup + per-row sum combine.
// row_offsets = arange(NNZ+1) here -> 1 nnz/row, i.e. a pure gather of 512 B
// rows from a 512 MB table. We keep the general CSR sum (start..end loop) for
// robustness; it degenerates to one iteration.
//
// V2b: latency-hiding restructure (V2 with the nontemporal-store type fixed:
// the builtin needs a clang ext_vector_type, not HIP's float4 class).
// Each thread owns U=4 rows; each level of the 3-deep load chain
// (offsets -> vals -> table) is batched across the 4 rows so 4 independent
// 512 B row gathers are in flight per wave-half at once. Output uses
// nontemporal stores (write-once data) to keep L2/LLC for table-row dups.
//
// Layout: 32 lanes per row, lane c handles float4 #c. Wave = 64 lanes = row
// pair {base+2u, base+2u+1} per unroll step -> every load/store instruction
// touches two contiguous 512 B segments (fully coalesced).

#define ROW_F4 32  // 128 floats = 32 float4 per row
#define U 4        // rows per thread (per half-wave)

typedef float f32x4 __attribute__((ext_vector_type(4)));

__global__ __launch_bounds__(256) void plugin_embedding_gather(
    const f32x4* __restrict__ table,
    const int*   __restrict__ row_offsets,
    const int*   __restrict__ vals,
    f32x4*       __restrict__ out,
    int n_rows)
{
    int t    = blockIdx.x * blockDim.x + threadIdx.x;
    int lane = t & 63;
    int col  = lane & 31;   // float4 slot within the row
    int half = lane >> 5;   // which row of the wave's pair
    long long wid = t >> 6; // global wave id
    int base = (int)(wid * (2 * U)) + half;  // rows: base, base+2, ..., base+2(U-1)

    int row[U], s[U], e[U], idx[U];
    bool live[U];

    // Level 1: batch all row_offsets loads (L2-resident, broadcast across lanes)
    #pragma unroll
    for (int u = 0; u < U; ++u) {
        row[u]  = base + 2 * u;
        live[u] = (row[u] < n_rows);
        if (live[u]) {
            s[u] = row_offsets[row[u]];
            e[u] = row_offsets[row[u] + 1];
        } else {
            s[u] = 0; e[u] = 0;
        }
    }

    // Level 2: batch all first-index loads
    #pragma unroll
    for (int u = 0; u < U; ++u)
        idx[u] = (s[u] < e[u]) ? vals[s[u]] : -1;

    // Level 3: batch all table-row gathers (4 independent 16 B loads/thread)
    f32x4 acc[U];
    #pragma unroll
    for (int u = 0; u < U; ++u) {
        if (idx[u] >= 0) {
            acc[u] = table[(size_t)idx[u] * ROW_F4 + col];
        } else {
            acc[u] = (f32x4)(0.f, 0.f, 0.f, 0.f);
        }
    }

    // General CSR tail (never taken when nnz==1/row, kept for robustness)
    #pragma unroll
    for (int u = 0; u < U; ++u) {
        for (int j = s[u] + 1; j < e[u]; ++j) {
            int id2 = vals[j];
            f32x4 v = table[(size_t)id2 * ROW_F4 + col];
            acc[u] += v;
        }
    }

    // Stores: write-once output, bypass L2 so table dups stay cached
    #pragma unroll
    for (int u = 0; u < U; ++u) {
        if (live[u]) {
            __builtin_nontemporal_store(acc[u], &out[(size_t)row[u] * ROW_F4 + col]);
        }
    }
}

extern "C" void kernel_launch(void* const* d_in, const int* in_sizes, int n_in,
                              void* d_out, int out_size, void* d_ws, size_t ws_size,
                              hipStream_t stream) {
    const f32x4* table       = (const f32x4*)d_in[0];
    const int*   row_offsets = (const int*)d_in[1];
    const int*   vals        = (const int*)d_in[2];
    f32x4*       out         = (f32x4*)d_out;

    // out_size = n_rows * 128 floats
    int n_rows = out_size / 128;

    // One wave handles 2*U rows.
    long long waves         = ((long long)n_rows + 2 * U - 1) / (2 * U);
    long long total_threads = waves * 64;
    int block = 256;
    int grid  = (int)((total_threads + block - 1) / block);

    plugin_embedding_gather<<<grid, block, 0, stream>>>(
        table, row_offsets, vals, out, n_rows);
}